// Round 1
// baseline (1583.904 us; speedup 1.0000x reference)
//
#include <hip/hip_runtime.h>
#include <cstdint>

#define HH 128
constexpr int cN_X   = 250000;
constexpr int cN_SRC = 50000;
constexpr int cN_Y   = 50000;
constexpr int cN_INT = 500000;
constexpr int cE_NODE = 1000000;
constexpr int cE_DOM  = 500000;

__device__ __forceinline__ float bf2f(unsigned short s) {
  union { unsigned u; float f; } v; v.u = ((unsigned)s) << 16; return v.f;
}
__device__ __forceinline__ unsigned short f2bf(float f) {
  union { float f; unsigned u; } v; v.f = f;
  unsigned r = v.u + 0x7fffu + ((v.u >> 16) & 1u);  // round-to-nearest-even
  return (unsigned short)(r >> 16);
}

// ---------------- segment-sum of x by sorted domain_indicator -> xsum [N_SRC][H]
// 128 threads = one channel each; 128 rows per block; plain stores for
// block-interior segments, atomics only for first/last (shared) segments.
__global__ __launch_bounds__(128) void k_segsum_x(const float* __restrict__ x,
                                                  const int* __restrict__ ind,
                                                  float* __restrict__ xsum) {
  __shared__ int sind[128];
  int base = blockIdx.x * 128;
  int c = threadIdx.x;
  int nrows = min(128, cN_X - base);
  if (threadIdx.x < nrows) sind[threadIdx.x] = ind[base + threadIdx.x];
  __syncthreads();
  float acc = 0.f;
  int cur = sind[0];
  bool started_inside = false;
  for (int r = 0; r < nrows; ++r) {
    int s = sind[r];
    if (s != cur) {
      if (started_inside) xsum[(size_t)cur * HH + c] = acc;      // exclusive to block
      else atomicAdd(&xsum[(size_t)cur * HH + c], acc);          // may span blocks
      cur = s; acc = 0.f; started_inside = true;
    }
    acc += x[(size_t)(base + r) * HH + c];
  }
  atomicAdd(&xsum[(size_t)cur * HH + c], acc);                    // last may span blocks
}

// ---------------- out[M][128] = A[M][128] @ W[128][128]^T  (W staged bf16-transposed in LDS)
__global__ __launch_bounds__(256, 2) void k_gemm128(const float* __restrict__ A,
                                                    const float* __restrict__ W,
                                                    float* __restrict__ out, int M) {
  __shared__ unsigned short sW[HH * HH];   // Wt[k][c], bf16, 32 KB
  __shared__ float sA[64 * HH];            // 32 KB
  int tid = threadIdx.x;
  int row0 = blockIdx.x * 64;
  int rows = min(64, M - row0);
  for (int i = tid; i < HH * HH / 4; i += 256) {
    int idx = i * 4; int c_ = idx >> 7, k_ = idx & 127;
    float4 w4 = *(const float4*)(W + idx);
    sW[(k_ + 0) * HH + c_] = f2bf(w4.x);
    sW[(k_ + 1) * HH + c_] = f2bf(w4.y);
    sW[(k_ + 2) * HH + c_] = f2bf(w4.z);
    sW[(k_ + 3) * HH + c_] = f2bf(w4.w);
  }
  for (int i = tid; i < rows * HH / 4; i += 256)
    *(float4*)(sA + i * 4) = *(const float4*)(A + (size_t)row0 * HH + i * 4);
  __syncthreads();
  int cg = tid & 31, eg = tid >> 5, c0 = cg * 4;
  float acc[8][4];
#pragma unroll
  for (int i = 0; i < 8; i++) { acc[i][0] = 0; acc[i][1] = 0; acc[i][2] = 0; acc[i][3] = 0; }
  for (int k = 0; k < HH; k++) {
    ushort4 u4 = *(const ushort4*)(sW + k * HH + c0);
    float w0 = bf2f(u4.x), w1 = bf2f(u4.y), w2 = bf2f(u4.z), w3 = bf2f(u4.w);
#pragma unroll
    for (int i = 0; i < 8; i++) {
      float a = sA[(eg * 8 + i) * HH + k];
      acc[i][0] += a * w0; acc[i][1] += a * w1; acc[i][2] += a * w2; acc[i][3] += a * w3;
    }
  }
#pragma unroll
  for (int i = 0; i < 8; i++) {
    int r = row0 + eg * 8 + i;
    if (r < M)
      *(float4*)(out + (size_t)r * HH + c0) =
          make_float4(acc[i][0], acc[i][1], acc[i][2], acc[i][3]);
  }
}

// ---------------- bnd[e] = lower_bound(intersect_indicator, e), e in [0, N_INT]
__global__ void k_bounds(const int* __restrict__ ii, int* __restrict__ bnd) {
  int e = blockIdx.x * blockDim.x + threadIdx.x;
  if (e > cN_INT) return;
  int lo = 0, hi = cE_NODE;
  while (lo < hi) { int mid = (lo + hi) >> 1; if (ii[mid] < e) lo = mid + 1; else hi = mid; }
  bnd[e] = lo;
}

// ---------------- CSR build for dme1
__global__ void k_hist(const int* __restrict__ dme1, int* __restrict__ cnt) {
  int e = blockIdx.x * blockDim.x + threadIdx.x;
  if (e < cE_DOM) atomicAdd(&cnt[dme1[e]], 1);
}
__global__ __launch_bounds__(256) void k_scan1(const int* __restrict__ cnt,
                                               int* __restrict__ bsum, int* __restrict__ excl) {
  __shared__ int buf[256];
  int i = blockIdx.x * 256 + threadIdx.x;
  int v = (i < cN_SRC) ? cnt[i] : 0;
  buf[threadIdx.x] = v; __syncthreads();
  for (int d = 1; d < 256; d <<= 1) {
    int t = (threadIdx.x >= d) ? buf[threadIdx.x - d] : 0;
    __syncthreads();
    buf[threadIdx.x] += t;
    __syncthreads();
  }
  if (i < cN_SRC) excl[i] = buf[threadIdx.x] - v;
  if (threadIdx.x == 255) bsum[blockIdx.x] = buf[255];
}
__global__ __launch_bounds__(256) void k_scan2(int* __restrict__ bsum, int nb) {
  __shared__ int buf[256];
  int v = (threadIdx.x < nb) ? bsum[threadIdx.x] : 0;
  buf[threadIdx.x] = v; __syncthreads();
  for (int d = 1; d < 256; d <<= 1) {
    int t = (threadIdx.x >= d) ? buf[threadIdx.x - d] : 0;
    __syncthreads();
    buf[threadIdx.x] += t;
    __syncthreads();
  }
  if (threadIdx.x < nb) bsum[threadIdx.x] = buf[threadIdx.x] - v;  // exclusive
}
__global__ void k_scan3(const int* __restrict__ excl, const int* __restrict__ bsum,
                        int* __restrict__ offs, int* __restrict__ cursor) {
  int i = blockIdx.x * 256 + threadIdx.x;
  if (i < cN_SRC) { int o = excl[i] + bsum[i >> 8]; offs[i] = o; cursor[i] = o; }
  else if (i == cN_SRC) offs[cN_SRC] = cE_DOM;
}
__global__ void k_scatter(const int* __restrict__ dme1, int* __restrict__ cursor,
                          int* __restrict__ eid) {
  int e = blockIdx.x * blockDim.x + threadIdx.x;
  if (e < cE_DOM) {
    int pos = atomicAdd(&cursor[dme1[e]], 1);
    eid[pos] = e;
  }
}

// ---------------- fused: gather-sum x rows into 64 bins, tile-GEMM with W_xint,
// add gathered x_sum_lin + y_lin, store msg (bf16), emit BN partial sums.
__global__ __launch_bounds__(256, 2) void k_fused(
    const float* __restrict__ x, const int* __restrict__ nme0,
    const int* __restrict__ ii, const int* __restrict__ bnd,
    const float* __restrict__ Wxint,
    const float* __restrict__ xsl, const float* __restrict__ yl,
    const int* __restrict__ dme0, const int* __restrict__ dme1,
    unsigned short* __restrict__ msg, float* __restrict__ partials) {
  __shared__ unsigned short sW[HH * HH];   // Wt[k][c] bf16, 32 KB
  __shared__ float sV[64 * HH];            // summed bin rows, 32 KB (reused for BN reduce)
  __shared__ int sB[65];
  int tid = threadIdx.x;
  int e0 = blockIdx.x * 64;
  int nvalid = min(64, cE_DOM - e0);
  if (tid <= 64) sB[tid] = bnd[min(e0 + tid, cN_INT)];
  for (int i = tid; i < HH * HH / 4; i += 256) {
    int idx = i * 4; int c_ = idx >> 7, k_ = idx & 127;
    float4 w4 = *(const float4*)(Wxint + idx);
    sW[(k_ + 0) * HH + c_] = f2bf(w4.x);
    sW[(k_ + 1) * HH + c_] = f2bf(w4.y);
    sW[(k_ + 2) * HH + c_] = f2bf(w4.z);
    sW[(k_ + 3) * HH + c_] = f2bf(w4.w);
  }
  for (int i = tid; i < 64 * HH / 4; i += 256)
    *(float4*)(sV + i * 4) = make_float4(0.f, 0.f, 0.f, 0.f);
  __syncthreads();

  int lane = tid & 63, wv = tid >> 6;
  int j0 = sB[0], j1 = sB[nvalid];
  for (int j = j0 + wv; j < j1; j += 4) {
    int row = nme0[j];
    int bin = ii[j] - e0;
    float2 f2 = *(const float2*)(x + (size_t)row * HH + lane * 2);
    atomicAdd(sV + bin * HH + lane * 2, f2.x);
    atomicAdd(sV + bin * HH + lane * 2 + 1, f2.y);
  }
  __syncthreads();

  int cg = tid & 31, eg = tid >> 5, c0 = cg * 4;
  float acc[8][4];
#pragma unroll
  for (int i = 0; i < 8; i++) { acc[i][0] = 0; acc[i][1] = 0; acc[i][2] = 0; acc[i][3] = 0; }
  for (int k = 0; k < HH; k++) {
    ushort4 u4 = *(const ushort4*)(sW + k * HH + c0);
    float w0 = bf2f(u4.x), w1 = bf2f(u4.y), w2 = bf2f(u4.z), w3 = bf2f(u4.w);
#pragma unroll
    for (int i = 0; i < 8; i++) {
      float a = sV[(eg * 8 + i) * HH + k];
      acc[i][0] += a * w0; acc[i][1] += a * w1; acc[i][2] += a * w2; acc[i][3] += a * w3;
    }
  }

  float bs0 = 0, bs1 = 0, bs2 = 0, bs3 = 0, bq0 = 0, bq1 = 0, bq2 = 0, bq3 = 0;
#pragma unroll
  for (int i = 0; i < 8; i++) {
    int le = eg * 8 + i;
    int e = e0 + le;
    if (le < nvalid) {
      int s = dme0[e], t = dme1[e];
      float4 xs = *(const float4*)(xsl + (size_t)s * HH + c0);
      float4 yy = *(const float4*)(yl + (size_t)t * HH + c0);
      float m0 = acc[i][0] + xs.x + yy.x;
      float m1 = acc[i][1] + xs.y + yy.y;
      float m2 = acc[i][2] + xs.z + yy.z;
      float m3 = acc[i][3] + xs.w + yy.w;
      ushort4 u; u.x = f2bf(m0); u.y = f2bf(m1); u.z = f2bf(m2); u.w = f2bf(m3);
      *(ushort4*)(msg + (size_t)e * HH + c0) = u;
      bs0 += m0; bs1 += m1; bs2 += m2; bs3 += m3;
      bq0 += m0 * m0; bq1 += m1 * m1; bq2 += m2 * m2; bq3 += m3 * m3;
    }
  }

  // BN partial reduction across the 8 edge-groups -> partials[block][2c+f]
  __syncthreads();
  float* sR = sV;
  sR[(eg * HH + c0 + 0) * 2 + 0] = bs0; sR[(eg * HH + c0 + 0) * 2 + 1] = bq0;
  sR[(eg * HH + c0 + 1) * 2 + 0] = bs1; sR[(eg * HH + c0 + 1) * 2 + 1] = bq1;
  sR[(eg * HH + c0 + 2) * 2 + 0] = bs2; sR[(eg * HH + c0 + 2) * 2 + 1] = bq2;
  sR[(eg * HH + c0 + 3) * 2 + 0] = bs3; sR[(eg * HH + c0 + 3) * 2 + 1] = bq3;
  __syncthreads();
  {
    float s = 0.f;
#pragma unroll
    for (int g = 0; g < 8; g++) s += sR[g * 256 + tid];
    partials[(size_t)blockIdx.x * 256 + tid] = s;
  }
}

// ---------------- BN stat reduction + scale/shift
__global__ __launch_bounds__(256) void k_bnred1(const float* __restrict__ partials,
                                                float* __restrict__ part2, int nb) {
  float s = 0.f;
  for (int b = blockIdx.x; b < nb; b += 64) s += partials[(size_t)b * 256 + threadIdx.x];
  part2[blockIdx.x * 256 + threadIdx.x] = s;
}
__global__ __launch_bounds__(256) void k_bnfinal(const float* __restrict__ part2,
                                                 const float* __restrict__ bnw,
                                                 const float* __restrict__ bnb,
                                                 float* __restrict__ ss) {
  __shared__ float L[256];
  float s = 0.f;
  for (int b = 0; b < 64; b++) s += part2[b * 256 + threadIdx.x];
  L[threadIdx.x] = s; __syncthreads();
  if (threadIdx.x < HH) {
    int c = threadIdx.x;
    float sum = L[2 * c], sq = L[2 * c + 1];
    float mean = sum / (float)cE_DOM;
    float var = sq / (float)cE_DOM - mean * mean;
    float sc = bnw[c] * rsqrtf(var + 1e-5f);
    float sh = bnb[c] - mean * sc;
    ss[2 * c] = sc; ss[2 * c + 1] = sh;
  }
}

// ---------------- final: one wave per target, sum relu(bn(msg)) over CSR edge list
__global__ __launch_bounds__(256) void k_out(const unsigned short* __restrict__ msg,
                                             const int* __restrict__ offs,
                                             const int* __restrict__ eid,
                                             const float* __restrict__ ss,
                                             float* __restrict__ out) {
  int wv = threadIdx.x >> 6, lane = threadIdx.x & 63;
  int t = blockIdx.x * 4 + wv;
  if (t >= cN_Y) return;
  int c0 = lane * 2;
  float sc0 = ss[c0 * 2 + 0], sh0 = ss[c0 * 2 + 1];
  float sc1 = ss[(c0 + 1) * 2 + 0], sh1 = ss[(c0 + 1) * 2 + 1];
  float a0 = 0.f, a1 = 0.f;
  int j0 = offs[t], j1 = offs[t + 1];
  for (int j = j0; j < j1; ++j) {
    int e = eid[j];
    ushort2 u = *(const ushort2*)(msg + (size_t)e * HH + c0);
    float m0 = fmaf(bf2f(u.x), sc0, sh0);
    float m1 = fmaf(bf2f(u.y), sc1, sh1);
    a0 += fmaxf(m0, 0.f);
    a1 += fmaxf(m1, 0.f);
  }
  *(float2*)(out + (size_t)t * HH + c0) = make_float2(a0, a1);
}

extern "C" void kernel_launch(void* const* d_in, const int* in_sizes, int n_in,
                              void* d_out, int out_size, void* d_ws, size_t ws_size,
                              hipStream_t stream) {
  const float* x     = (const float*)d_in[0];
  const float* y     = (const float*)d_in[1];
  const int* dom_ind = (const int*)d_in[2];
  const int* nme     = (const int*)d_in[3];   // [2][E_NODE]; row 0 used
  const int* ii      = (const int*)d_in[4];
  const int* dme     = (const int*)d_in[5];   // [2][E_DOM]
  const float* Wxsum = (const float*)d_in[6];
  const float* Wxint = (const float*)d_in[7];
  const float* Wy    = (const float*)d_in[8];
  const float* bnw   = (const float*)d_in[9];
  const float* bnb   = (const float*)d_in[10];
  float* out = (float*)d_out;

  char* ws = (char*)d_ws;
  size_t o = 0;
  auto alloc = [&](size_t bytes) -> void* {
    void* p = ws + o;
    o = (o + bytes + 255) & ~(size_t)255;
    return p;
  };
  float* xsum   = (float*)alloc((size_t)cN_SRC * HH * 4);
  float* xsl    = (float*)alloc((size_t)cN_SRC * HH * 4);
  float* ylin   = (float*)alloc((size_t)cN_Y * HH * 4);
  unsigned short* msg = (unsigned short*)alloc((size_t)cE_DOM * HH * 2);
  int* bnd      = (int*)alloc((size_t)(cN_INT + 1) * 4);
  int* cnt      = (int*)alloc((size_t)cN_SRC * 4);
  int* excl     = (int*)alloc((size_t)cN_SRC * 4);
  int* bsum     = (int*)alloc(256 * 4);
  int* offs     = (int*)alloc((size_t)(cN_SRC + 1) * 4);
  int* cursor   = (int*)alloc((size_t)cN_SRC * 4);
  int* eid      = (int*)alloc((size_t)cE_DOM * 4);
  const int nfb = (cE_DOM + 63) / 64;          // 7813 fused blocks
  float* partials = (float*)alloc((size_t)nfb * 256 * 4);
  float* part2  = (float*)alloc(64 * 256 * 4);
  float* ssbuf  = (float*)alloc(256 * 4);

  hipMemsetAsync(xsum, 0, (size_t)cN_SRC * HH * 4, stream);
  hipMemsetAsync(cnt, 0, (size_t)cN_SRC * 4, stream);

  k_segsum_x<<<(cN_X + 127) / 128, 128, 0, stream>>>(x, dom_ind, xsum);
  k_gemm128<<<(cN_SRC + 63) / 64, 256, 0, stream>>>(xsum, Wxsum, xsl, cN_SRC);
  k_gemm128<<<(cN_Y + 63) / 64, 256, 0, stream>>>(y, Wy, ylin, cN_Y);
  k_bounds<<<(cN_INT + 1 + 255) / 256, 256, 0, stream>>>(ii, bnd);
  k_hist<<<(cE_DOM + 255) / 256, 256, 0, stream>>>(dme + cE_DOM, cnt);
  k_scan1<<<(cN_SRC + 255) / 256, 256, 0, stream>>>(cnt, bsum, excl);
  k_scan2<<<1, 256, 0, stream>>>(bsum, (cN_SRC + 255) / 256);
  k_scan3<<<(cN_SRC + 1 + 255) / 256, 256, 0, stream>>>(excl, bsum, offs, cursor);
  k_scatter<<<(cE_DOM + 255) / 256, 256, 0, stream>>>(dme + cE_DOM, cursor, eid);
  k_fused<<<nfb, 256, 0, stream>>>(x, nme, ii, bnd, Wxint, xsl, ylin,
                                   dme, dme + cE_DOM, msg, partials);
  k_bnred1<<<64, 256, 0, stream>>>(partials, part2, nfb);
  k_bnfinal<<<1, 256, 0, stream>>>(part2, bnw, bnb, ssbuf);
  k_out<<<(cN_Y + 3) / 4, 256, 0, stream>>>(msg, offs, eid, ssbuf, out);
}

// Round 2
// 1199.572 us; speedup vs baseline: 1.3204x; 1.3204x over previous
//
#include <hip/hip_runtime.h>
#include <cstdint>

#define HH 128
#define SV 132  // padded f32 LDS row stride: 16B-aligned rows, bank-balanced b128 reads
constexpr int cN_X   = 250000;
constexpr int cN_SRC = 50000;
constexpr int cN_Y   = 50000;
constexpr int cN_INT = 500000;
constexpr int cE_NODE = 1000000;
constexpr int cE_DOM  = 500000;

typedef __attribute__((ext_vector_type(8))) short bf16x8;
typedef __attribute__((ext_vector_type(4))) float f32x4;

__device__ __forceinline__ float bf2f(unsigned short s) {
  union { unsigned u; float f; } v; v.u = ((unsigned)s) << 16; return v.f;
}
__device__ __forceinline__ unsigned short f2bf(float f) {
  union { float f; unsigned u; } v; v.f = f;
  unsigned r = v.u + 0x7fffu + ((v.u >> 16) & 1u);  // RNE
  return (unsigned short)(r >> 16);
}

// ---------------- cast the three W matrices to bf16 (row-major) once
__global__ __launch_bounds__(256) void k_wcast(const float* __restrict__ w0,
                                               const float* __restrict__ w1,
                                               const float* __restrict__ w2,
                                               unsigned short* __restrict__ dst) {
  int i = blockIdx.x * 256 + threadIdx.x;       // 48 blocks: 12288 threads x 4 elems
  int idx4 = i * 4;
  int mat = idx4 >> 14;                          // 16384 elems per matrix
  int off = idx4 & 16383;
  const float* src = (mat == 0) ? w0 : (mat == 1) ? w1 : w2;
  float4 v = *(const float4*)(src + off);
  ushort4 u;
  u.x = f2bf(v.x); u.y = f2bf(v.y); u.z = f2bf(v.z); u.w = f2bf(v.w);
  *(ushort4*)(dst + (size_t)mat * 16384 + off) = u;
}

// ---------------- segment-sum of x by sorted domain_indicator -> xsum [N_SRC][H]
__global__ __launch_bounds__(128) void k_segsum_x(const float* __restrict__ x,
                                                  const int* __restrict__ ind,
                                                  float* __restrict__ xsum) {
  __shared__ int sind[128];
  int base = blockIdx.x * 128;
  int c = threadIdx.x;
  int nrows = min(128, cN_X - base);
  if (threadIdx.x < nrows) sind[threadIdx.x] = ind[base + threadIdx.x];
  __syncthreads();
  float acc = 0.f;
  int cur = sind[0];
  bool started_inside = false;
  for (int r = 0; r < nrows; ++r) {
    int s = sind[r];
    if (s != cur) {
      if (started_inside) xsum[(size_t)cur * HH + c] = acc;
      else atomicAdd(&xsum[(size_t)cur * HH + c], acc);
      cur = s; acc = 0.f; started_inside = true;
    }
    acc += x[(size_t)(base + r) * HH + c];
  }
  atomicAdd(&xsum[(size_t)cur * HH + c], acc);
}

// ---------------- MFMA helper: load B frags for this wave (cols wv*32..wv*32+31)
__device__ __forceinline__ void load_bfrags(const unsigned short* __restrict__ Wbf,
                                            int wv, int lane, bf16x8 bfrag[2][4]) {
  int cbase = wv * 32 + (lane & 15);
  int krow = (lane >> 4) * 8;
#pragma unroll
  for (int ct = 0; ct < 2; ct++)
#pragma unroll
    for (int kt = 0; kt < 4; kt++)
      bfrag[ct][kt] = *(const bf16x8*)(Wbf + (size_t)(cbase + ct * 16) * HH + kt * 32 + krow);
}

// A-frag: read 8 f32 from padded LDS row, convert to bf16x8
__device__ __forceinline__ bf16x8 make_afrag(const float* __restrict__ ap) {
  f32x4 f0 = *(const f32x4*)ap;
  f32x4 f1 = *(const f32x4*)(ap + 4);
  bf16x8 a;
  a[0] = (short)f2bf(f0[0]); a[1] = (short)f2bf(f0[1]);
  a[2] = (short)f2bf(f0[2]); a[3] = (short)f2bf(f0[3]);
  a[4] = (short)f2bf(f1[0]); a[5] = (short)f2bf(f1[1]);
  a[6] = (short)f2bf(f1[2]); a[7] = (short)f2bf(f1[3]);
  return a;
}

// ---------------- out[M][128] = A[M][128] @ W^T via MFMA (Wbf = bf16 W row-major)
__global__ __launch_bounds__(256, 4) void k_gemm128(const float* __restrict__ A,
                                                    const unsigned short* __restrict__ Wbf,
                                                    float* __restrict__ out, int M) {
  __shared__ float sA[64 * SV];
  int tid = threadIdx.x, lane = tid & 63, wv = tid >> 6;
  int row0 = blockIdx.x * 64;
  int rows = min(64, M - row0);
  bf16x8 bfrag[2][4];
  load_bfrags(Wbf, wv, lane, bfrag);
  for (int i = tid; i < 64 * 32; i += 256) {
    int idx = i * 4, r = idx >> 7, c = idx & 127;
    f32x4 v = {0.f, 0.f, 0.f, 0.f};
    if (r < rows) {
      float4 g = *(const float4*)(A + (size_t)(row0 + r) * HH + c);
      v[0] = g.x; v[1] = g.y; v[2] = g.z; v[3] = g.w;
    }
    *(f32x4*)(&sA[r * SV + c]) = v;
  }
  __syncthreads();
  int m = lane & 15, q = lane >> 4;
  f32x4 acc[4][2];
#pragma unroll
  for (int rt = 0; rt < 4; rt++)
#pragma unroll
    for (int ct = 0; ct < 2; ct++) acc[rt][ct] = (f32x4){0.f, 0.f, 0.f, 0.f};
#pragma unroll
  for (int kt = 0; kt < 4; kt++) {
    int kof = kt * 32 + q * 8;
#pragma unroll
    for (int rt = 0; rt < 4; rt++) {
      bf16x8 af = make_afrag(&sA[(rt * 16 + m) * SV + kof]);
      acc[rt][0] = __builtin_amdgcn_mfma_f32_16x16x32_bf16(af, bfrag[0][kt], acc[rt][0], 0, 0, 0);
      acc[rt][1] = __builtin_amdgcn_mfma_f32_16x16x32_bf16(af, bfrag[1][kt], acc[rt][1], 0, 0, 0);
    }
  }
#pragma unroll
  for (int rt = 0; rt < 4; rt++)
#pragma unroll
    for (int ct = 0; ct < 2; ct++)
#pragma unroll
      for (int rg = 0; rg < 4; rg++) {
        int r = rt * 16 + q * 4 + rg;
        if (r < rows)
          out[(size_t)(row0 + r) * HH + wv * 32 + ct * 16 + m] = acc[rt][ct][rg];
      }
}

// ---------------- bnd[e] = lower_bound(intersect_indicator, e)
__global__ void k_bounds(const int* __restrict__ ii, int* __restrict__ bnd) {
  int e = blockIdx.x * blockDim.x + threadIdx.x;
  if (e > cN_INT) return;
  int lo = 0, hi = cE_NODE;
  while (lo < hi) { int mid = (lo + hi) >> 1; if (ii[mid] < e) lo = mid + 1; else hi = mid; }
  bnd[e] = lo;
}

// ---------------- CSR build for dme1
__global__ void k_hist(const int* __restrict__ dme1, int* __restrict__ cnt) {
  int e = blockIdx.x * blockDim.x + threadIdx.x;
  if (e < cE_DOM) atomicAdd(&cnt[dme1[e]], 1);
}
__global__ __launch_bounds__(256) void k_scan1(const int* __restrict__ cnt,
                                               int* __restrict__ bsum, int* __restrict__ excl) {
  __shared__ int buf[256];
  int i = blockIdx.x * 256 + threadIdx.x;
  int v = (i < cN_SRC) ? cnt[i] : 0;
  buf[threadIdx.x] = v; __syncthreads();
  for (int d = 1; d < 256; d <<= 1) {
    int t = (threadIdx.x >= d) ? buf[threadIdx.x - d] : 0;
    __syncthreads();
    buf[threadIdx.x] += t;
    __syncthreads();
  }
  if (i < cN_SRC) excl[i] = buf[threadIdx.x] - v;
  if (threadIdx.x == 255) bsum[blockIdx.x] = buf[255];
}
__global__ __launch_bounds__(256) void k_scan2(int* __restrict__ bsum, int nb) {
  __shared__ int buf[256];
  int v = (threadIdx.x < nb) ? bsum[threadIdx.x] : 0;
  buf[threadIdx.x] = v; __syncthreads();
  for (int d = 1; d < 256; d <<= 1) {
    int t = (threadIdx.x >= d) ? buf[threadIdx.x - d] : 0;
    __syncthreads();
    buf[threadIdx.x] += t;
    __syncthreads();
  }
  if (threadIdx.x < nb) bsum[threadIdx.x] = buf[threadIdx.x] - v;
}
__global__ void k_scan3(const int* __restrict__ excl, const int* __restrict__ bsum,
                        int* __restrict__ offs, int* __restrict__ cursor) {
  int i = blockIdx.x * 256 + threadIdx.x;
  if (i < cN_SRC) { int o = excl[i] + bsum[i >> 8]; offs[i] = o; cursor[i] = o; }
  else if (i == cN_SRC) offs[cN_SRC] = cE_DOM;
}
__global__ void k_scatter(const int* __restrict__ dme1, int* __restrict__ cursor,
                          int* __restrict__ eid) {
  int e = blockIdx.x * blockDim.x + threadIdx.x;
  if (e < cE_DOM) {
    int pos = atomicAdd(&cursor[dme1[e]], 1);
    eid[pos] = e;
  }
}

// ---------------- fused: gather-sum x into 64 bins (LDS f32 atomics), MFMA with
// W_xint (B frags in regs from global bf16), add gathers, bf16 msg, BN partials.
__global__ __launch_bounds__(256, 4) void k_fused(
    const float* __restrict__ x, const int* __restrict__ nme0,
    const int* __restrict__ ii, const int* __restrict__ bnd,
    const unsigned short* __restrict__ Wbf,
    const float* __restrict__ xsl, const float* __restrict__ yl,
    const int* __restrict__ dme0, const int* __restrict__ dme1,
    unsigned short* __restrict__ msg, float* __restrict__ partials) {
  __shared__ float sV[64 * SV];   // 33.8 KB
  __shared__ float sBN[4 * 256];  // 4 KB
  __shared__ int sIdx[512];       // 2 KB
  int tid = threadIdx.x, lane = tid & 63, wv = tid >> 6;
  int e0 = blockIdx.x * 64;
  int nvalid = min(64, cE_DOM - e0);
  int j0 = bnd[e0], j1 = bnd[e0 + nvalid];

  for (int i = tid; i < 64 * SV; i += 256) sV[i] = 0.f;
  bf16x8 bfrag[2][4];
  load_bfrags(Wbf, wv, lane, bfrag);
  __syncthreads();

  // gather phase: chunk indices through LDS, 2-edge unrolled per wave
  for (int jb = j0; jb < j1; jb += 256) {
    int cn = min(256, j1 - jb);
    if (tid < cn) { sIdx[tid] = nme0[jb + tid]; sIdx[256 + tid] = ii[jb + tid] - e0; }
    __syncthreads();
    int jj = wv;
    for (; jj + 4 < cn; jj += 8) {
      int r0 = sIdx[jj], b0 = sIdx[256 + jj];
      int r1 = sIdx[jj + 4], b1 = sIdx[256 + jj + 4];
      float a0 = x[((size_t)r0 << 7) + lane];
      float a1 = x[((size_t)r0 << 7) + 64 + lane];
      float a2 = x[((size_t)r1 << 7) + lane];
      float a3 = x[((size_t)r1 << 7) + 64 + lane];
      atomicAdd(&sV[b0 * SV + lane], a0);
      atomicAdd(&sV[b0 * SV + 64 + lane], a1);
      atomicAdd(&sV[b1 * SV + lane], a2);
      atomicAdd(&sV[b1 * SV + 64 + lane], a3);
    }
    if (jj < cn) {
      int r0 = sIdx[jj], b0 = sIdx[256 + jj];
      float a0 = x[((size_t)r0 << 7) + lane];
      float a1 = x[((size_t)r0 << 7) + 64 + lane];
      atomicAdd(&sV[b0 * SV + lane], a0);
      atomicAdd(&sV[b0 * SV + 64 + lane], a1);
    }
    __syncthreads();
  }
  __syncthreads();  // covers the j0==j1 case (zero-init visibility)

  // MFMA: 64x128 @ 128x128
  int m = lane & 15, q = lane >> 4;
  f32x4 acc[4][2];
#pragma unroll
  for (int rt = 0; rt < 4; rt++)
#pragma unroll
    for (int ct = 0; ct < 2; ct++) acc[rt][ct] = (f32x4){0.f, 0.f, 0.f, 0.f};
#pragma unroll
  for (int kt = 0; kt < 4; kt++) {
    int kof = kt * 32 + q * 8;
#pragma unroll
    for (int rt = 0; rt < 4; rt++) {
      bf16x8 af = make_afrag(&sV[(rt * 16 + m) * SV + kof]);
      acc[rt][0] = __builtin_amdgcn_mfma_f32_16x16x32_bf16(af, bfrag[0][kt], acc[rt][0], 0, 0, 0);
      acc[rt][1] = __builtin_amdgcn_mfma_f32_16x16x32_bf16(af, bfrag[1][kt], acc[rt][1], 0, 0, 0);
    }
  }
  __syncthreads();
  // C -> sV (f32)
#pragma unroll
  for (int rt = 0; rt < 4; rt++)
#pragma unroll
    for (int ct = 0; ct < 2; ct++)
#pragma unroll
      for (int rg = 0; rg < 4; rg++)
        sV[(rt * 16 + q * 4 + rg) * SV + wv * 32 + ct * 16 + m] = acc[rt][ct][rg];
  __syncthreads();

  // epilogue: wave per edge, coalesced gathers, bf16 msg, BN per-lane partials
  float s0 = 0.f, s1 = 0.f, q0 = 0.f, q1 = 0.f;
  int c0 = lane * 2;
  for (int i = 0; i < 16; i++) {
    int le = wv + i * 4;
    int e = e0 + le;
    if (le < nvalid) {
      int s = dme0[e], t = dme1[e];
      float2 xs = *(const float2*)(xsl + (size_t)s * HH + c0);
      float2 yy = *(const float2*)(yl + (size_t)t * HH + c0);
      float m0 = sV[le * SV + c0] + xs.x + yy.x;
      float m1 = sV[le * SV + c0 + 1] + xs.y + yy.y;
      ushort2 u; u.x = f2bf(m0); u.y = f2bf(m1);
      *(ushort2*)(msg + (size_t)e * HH + c0) = u;
      s0 += m0; s1 += m1; q0 += m0 * m0; q1 += m1 * m1;
    }
  }
  *(float4*)(&sBN[wv * 256 + lane * 4]) = make_float4(s0, q0, s1, q1);
  __syncthreads();
  partials[(size_t)blockIdx.x * 256 + tid] =
      sBN[tid] + sBN[256 + tid] + sBN[512 + tid] + sBN[768 + tid];
}

// ---------------- BN stat reduction + scale/shift
__global__ __launch_bounds__(256) void k_bnred1(const float* __restrict__ partials,
                                                float* __restrict__ part2, int nb) {
  float s = 0.f;
  for (int b = blockIdx.x; b < nb; b += 64) s += partials[(size_t)b * 256 + threadIdx.x];
  part2[blockIdx.x * 256 + threadIdx.x] = s;
}
__global__ __launch_bounds__(256) void k_bnfinal(const float* __restrict__ part2,
                                                 const float* __restrict__ bnw,
                                                 const float* __restrict__ bnb,
                                                 float* __restrict__ ss) {
  __shared__ float L[256];
  float s = 0.f;
  for (int b = 0; b < 64; b++) s += part2[b * 256 + threadIdx.x];
  L[threadIdx.x] = s; __syncthreads();
  if (threadIdx.x < HH) {
    int c = threadIdx.x;
    float sum = L[2 * c], sq = L[2 * c + 1];
    float mean = sum / (float)cE_DOM;
    float var = sq / (float)cE_DOM - mean * mean;
    float sc = bnw[c] * rsqrtf(var + 1e-5f);
    float sh = bnb[c] - mean * sc;
    ss[2 * c] = sc; ss[2 * c + 1] = sh;
  }
}

// ---------------- final: one wave per target, sum relu(bn(msg)) over CSR edges
__global__ __launch_bounds__(256) void k_out(const unsigned short* __restrict__ msg,
                                             const int* __restrict__ offs,
                                             const int* __restrict__ eid,
                                             const float* __restrict__ ss,
                                             float* __restrict__ out) {
  int wv = threadIdx.x >> 6, lane = threadIdx.x & 63;
  int t = blockIdx.x * 4 + wv;
  if (t >= cN_Y) return;
  int c0 = lane * 2;
  float sc0 = ss[c0 * 2 + 0], sh0 = ss[c0 * 2 + 1];
  float sc1 = ss[(c0 + 1) * 2 + 0], sh1 = ss[(c0 + 1) * 2 + 1];
  float a0 = 0.f, a1 = 0.f;
  int j0 = offs[t], j1 = offs[t + 1];
  for (int j = j0; j < j1; ++j) {
    int e = eid[j];
    ushort2 u = *(const ushort2*)(msg + (size_t)e * HH + c0);
    float m0 = fmaf(bf2f(u.x), sc0, sh0);
    float m1 = fmaf(bf2f(u.y), sc1, sh1);
    a0 += fmaxf(m0, 0.f);
    a1 += fmaxf(m1, 0.f);
  }
  *(float2*)(out + (size_t)t * HH + c0) = make_float2(a0, a1);
}

extern "C" void kernel_launch(void* const* d_in, const int* in_sizes, int n_in,
                              void* d_out, int out_size, void* d_ws, size_t ws_size,
                              hipStream_t stream) {
  const float* x     = (const float*)d_in[0];
  const float* y     = (const float*)d_in[1];
  const int* dom_ind = (const int*)d_in[2];
  const int* nme     = (const int*)d_in[3];
  const int* ii      = (const int*)d_in[4];
  const int* dme     = (const int*)d_in[5];
  const float* Wxsum = (const float*)d_in[6];
  const float* Wxint = (const float*)d_in[7];
  const float* Wy    = (const float*)d_in[8];
  const float* bnw   = (const float*)d_in[9];
  const float* bnb   = (const float*)d_in[10];
  float* out = (float*)d_out;

  char* ws = (char*)d_ws;
  size_t o = 0;
  auto alloc = [&](size_t bytes) -> void* {
    void* p = ws + o;
    o = (o + bytes + 255) & ~(size_t)255;
    return p;
  };
  float* xsum   = (float*)alloc((size_t)cN_SRC * HH * 4);
  float* xsl    = (float*)alloc((size_t)cN_SRC * HH * 4);
  float* ylin   = (float*)alloc((size_t)cN_Y * HH * 4);
  unsigned short* msg = (unsigned short*)alloc((size_t)cE_DOM * HH * 2);
  int* bnd      = (int*)alloc((size_t)(cN_INT + 1) * 4);
  int* cnt      = (int*)alloc((size_t)cN_SRC * 4);
  int* excl     = (int*)alloc((size_t)cN_SRC * 4);
  int* bsum     = (int*)alloc(256 * 4);
  int* offs     = (int*)alloc((size_t)(cN_SRC + 1) * 4);
  int* cursor   = (int*)alloc((size_t)cN_SRC * 4);
  int* eid      = (int*)alloc((size_t)cE_DOM * 4);
  const int nfb = (cE_DOM + 63) / 64;
  float* partials = (float*)alloc((size_t)nfb * 256 * 4);
  float* part2  = (float*)alloc(64 * 256 * 4);
  float* ssbuf  = (float*)alloc(256 * 4);
  unsigned short* Wbf = (unsigned short*)alloc(3 * 16384 * 2);

  hipMemsetAsync(xsum, 0, (size_t)cN_SRC * HH * 4, stream);
  hipMemsetAsync(cnt, 0, (size_t)cN_SRC * 4, stream);

  k_wcast<<<48, 256, 0, stream>>>(Wxsum, Wy, Wxint, Wbf);
  k_segsum_x<<<(cN_X + 127) / 128, 128, 0, stream>>>(x, dom_ind, xsum);
  k_gemm128<<<(cN_SRC + 63) / 64, 256, 0, stream>>>(xsum, Wbf, xsl, cN_SRC);
  k_gemm128<<<(cN_Y + 63) / 64, 256, 0, stream>>>(y, Wbf + 16384, ylin, cN_Y);
  k_bounds<<<(cN_INT + 1 + 255) / 256, 256, 0, stream>>>(ii, bnd);
  k_hist<<<(cE_DOM + 255) / 256, 256, 0, stream>>>(dme + cE_DOM, cnt);
  k_scan1<<<(cN_SRC + 255) / 256, 256, 0, stream>>>(cnt, bsum, excl);
  k_scan2<<<1, 256, 0, stream>>>(bsum, (cN_SRC + 255) / 256);
  k_scan3<<<(cN_SRC + 1 + 255) / 256, 256, 0, stream>>>(excl, bsum, offs, cursor);
  k_scatter<<<(cE_DOM + 255) / 256, 256, 0, stream>>>(dme + cE_DOM, cursor, eid);
  k_fused<<<nfb, 256, 0, stream>>>(x, nme, ii, bnd, Wbf + 32768, xsl, ylin,
                                   dme, dme + cE_DOM, msg, partials);
  k_bnred1<<<64, 256, 0, stream>>>(partials, part2, nfb);
  k_bnfinal<<<1, 256, 0, stream>>>(part2, bnw, bnb, ssbuf);
  k_out<<<(cN_Y + 3) / 4, 256, 0, stream>>>(msg, offs, eid, ssbuf, out);
}

// Round 3
// 1172.354 us; speedup vs baseline: 1.3510x; 1.0232x over previous
//
#include <hip/hip_runtime.h>
#include <cstdint>

#define HH 128
#define SV 132  // padded f32 LDS row stride for GEMM A tiles
constexpr int cN_X   = 250000;
constexpr int cN_SRC = 50000;
constexpr int cN_Y   = 50000;
constexpr int cN_INT = 500000;
constexpr int cE_NODE = 1000000;
constexpr int cE_DOM  = 500000;

typedef __attribute__((ext_vector_type(8))) short bf16x8;
typedef __attribute__((ext_vector_type(4))) float f32x4;

__device__ __forceinline__ float bf2f(unsigned short s) {
  union { unsigned u; float f; } v; v.u = ((unsigned)s) << 16; return v.f;
}
__device__ __forceinline__ unsigned short f2bf(float f) {
  union { float f; unsigned u; } v; v.f = f;
  unsigned r = v.u + 0x7fffu + ((v.u >> 16) & 1u);  // RNE
  return (unsigned short)(r >> 16);
}

// ---------------- cast the three W matrices to bf16 (row-major) once
__global__ __launch_bounds__(256) void k_wcast(const float* __restrict__ w0,
                                               const float* __restrict__ w1,
                                               const float* __restrict__ w2,
                                               unsigned short* __restrict__ dst) {
  int i = blockIdx.x * 256 + threadIdx.x;
  int idx4 = i * 4;
  int mat = idx4 >> 14;
  int off = idx4 & 16383;
  const float* src = (mat == 0) ? w0 : (mat == 1) ? w1 : w2;
  float4 v = *(const float4*)(src + off);
  ushort4 u;
  u.x = f2bf(v.x); u.y = f2bf(v.y); u.z = f2bf(v.z); u.w = f2bf(v.w);
  *(ushort4*)(dst + (size_t)mat * 16384 + off) = u;
}

// ---------------- segment-sum of x by sorted domain_indicator -> xsum [N_SRC][H]
// 4 waves/block, each wave owns a 64-row chunk; float2 per lane; 4-row load batches.
__global__ __launch_bounds__(256) void k_segsum_x(const float* __restrict__ x,
                                                  const int* __restrict__ ind,
                                                  float* __restrict__ xsum) {
  __shared__ int sind[256];
  int tid = threadIdx.x, lane = tid & 63, wv = tid >> 6;
  int blk = blockIdx.x * 256;
  if (blk + tid < cN_X) sind[tid] = ind[blk + tid];
  __syncthreads();
  int base = blk + wv * 64;
  if (base >= cN_X) return;
  int nrows = min(64, cN_X - base);
  int c0 = lane * 2;
  float a0 = 0.f, a1 = 0.f;
  int cur = sind[wv * 64];
  bool inside = false;
  for (int r0 = 0; r0 < nrows; r0 += 4) {
    int nb = min(4, nrows - r0);
    float2 v[4];
#pragma unroll
    for (int k = 0; k < 4; k++)
      if (k < nb) v[k] = *(const float2*)(x + (size_t)(base + r0 + k) * HH + c0);
#pragma unroll
    for (int k = 0; k < 4; k++) {
      if (k < nb) {
        int s = sind[wv * 64 + r0 + k];
        if (s != cur) {
          if (inside) {
            xsum[(size_t)cur * HH + c0] = a0;
            xsum[(size_t)cur * HH + c0 + 1] = a1;
          } else {
            atomicAdd(&xsum[(size_t)cur * HH + c0], a0);
            atomicAdd(&xsum[(size_t)cur * HH + c0 + 1], a1);
          }
          cur = s; a0 = 0.f; a1 = 0.f; inside = true;
        }
        a0 += v[k].x; a1 += v[k].y;
      }
    }
  }
  atomicAdd(&xsum[(size_t)cur * HH + c0], a0);
  atomicAdd(&xsum[(size_t)cur * HH + c0 + 1], a1);
}

// ---------------- MFMA helper: load B frags for this wave (cols wv*32..wv*32+31)
__device__ __forceinline__ void load_bfrags(const unsigned short* __restrict__ Wbf,
                                            int wv, int lane, bf16x8 bfrag[2][4]) {
  int cbase = wv * 32 + (lane & 15);
  int krow = (lane >> 4) * 8;
#pragma unroll
  for (int ct = 0; ct < 2; ct++)
#pragma unroll
    for (int kt = 0; kt < 4; kt++)
      bfrag[ct][kt] = *(const bf16x8*)(Wbf + (size_t)(cbase + ct * 16) * HH + kt * 32 + krow);
}

__device__ __forceinline__ bf16x8 make_afrag(const float* __restrict__ ap) {
  f32x4 f0 = *(const f32x4*)ap;
  f32x4 f1 = *(const f32x4*)(ap + 4);
  bf16x8 a;
  a[0] = (short)f2bf(f0[0]); a[1] = (short)f2bf(f0[1]);
  a[2] = (short)f2bf(f0[2]); a[3] = (short)f2bf(f0[3]);
  a[4] = (short)f2bf(f1[0]); a[5] = (short)f2bf(f1[1]);
  a[6] = (short)f2bf(f1[2]); a[7] = (short)f2bf(f1[3]);
  return a;
}

// ---------------- outb[M][128] (bf16) = A[M][128] @ W^T via MFMA
__global__ __launch_bounds__(256, 4) void k_gemm128b(const float* __restrict__ A,
                                                     const unsigned short* __restrict__ Wbf,
                                                     unsigned short* __restrict__ outb, int M) {
  __shared__ float sA[64 * SV];
  int tid = threadIdx.x, lane = tid & 63, wv = tid >> 6;
  int row0 = blockIdx.x * 64;
  int rows = min(64, M - row0);
  bf16x8 bfrag[2][4];
  load_bfrags(Wbf, wv, lane, bfrag);
  for (int i = tid; i < 64 * 32; i += 256) {
    int idx = i * 4, r = idx >> 7, c = idx & 127;
    f32x4 v = {0.f, 0.f, 0.f, 0.f};
    if (r < rows) {
      float4 g = *(const float4*)(A + (size_t)(row0 + r) * HH + c);
      v[0] = g.x; v[1] = g.y; v[2] = g.z; v[3] = g.w;
    }
    *(f32x4*)(&sA[r * SV + c]) = v;
  }
  __syncthreads();
  int m = lane & 15, q = lane >> 4;
  f32x4 acc[4][2];
#pragma unroll
  for (int rt = 0; rt < 4; rt++)
#pragma unroll
    for (int ct = 0; ct < 2; ct++) acc[rt][ct] = (f32x4){0.f, 0.f, 0.f, 0.f};
#pragma unroll
  for (int kt = 0; kt < 4; kt++) {
    int kof = kt * 32 + q * 8;
#pragma unroll
    for (int rt = 0; rt < 4; rt++) {
      bf16x8 af = make_afrag(&sA[(rt * 16 + m) * SV + kof]);
      acc[rt][0] = __builtin_amdgcn_mfma_f32_16x16x32_bf16(af, bfrag[0][kt], acc[rt][0], 0, 0, 0);
      acc[rt][1] = __builtin_amdgcn_mfma_f32_16x16x32_bf16(af, bfrag[1][kt], acc[rt][1], 0, 0, 0);
    }
  }
  __syncthreads();
  unsigned short* sC = (unsigned short*)sA;
#pragma unroll
  for (int rt = 0; rt < 4; rt++)
#pragma unroll
    for (int ct = 0; ct < 2; ct++)
#pragma unroll
      for (int rg = 0; rg < 4; rg++) {
        int r = rt * 16 + q * 4 + rg;
        sC[r * HH + wv * 32 + ct * 16 + m] = f2bf(acc[rt][ct][rg]);
      }
  __syncthreads();
  for (int i = tid; i < rows * 16; i += 256) {
    int r = i >> 4, g = i & 15;
    ((uint4*)(outb + (size_t)(row0 + r) * HH))[g] = ((const uint4*)(sC + r * HH))[g];
  }
}

// ---------------- bnd[e] = lower_bound(intersect_indicator, e)
__global__ void k_bounds(const int* __restrict__ ii, int* __restrict__ bnd) {
  int e = blockIdx.x * blockDim.x + threadIdx.x;
  if (e > cN_INT) return;
  int lo = 0, hi = cE_NODE;
  while (lo < hi) { int mid = (lo + hi) >> 1; if (ii[mid] < e) lo = mid + 1; else hi = mid; }
  bnd[e] = lo;
}

// ---------------- CSR build for dme1
__global__ void k_hist(const int* __restrict__ dme1, int* __restrict__ cnt) {
  int e = blockIdx.x * blockDim.x + threadIdx.x;
  if (e < cE_DOM) atomicAdd(&cnt[dme1[e]], 1);
}
__global__ __launch_bounds__(256) void k_scan1(const int* __restrict__ cnt,
                                               int* __restrict__ bsum, int* __restrict__ excl) {
  __shared__ int buf[256];
  int i = blockIdx.x * 256 + threadIdx.x;
  int v = (i < cN_SRC) ? cnt[i] : 0;
  buf[threadIdx.x] = v; __syncthreads();
  for (int d = 1; d < 256; d <<= 1) {
    int t = (threadIdx.x >= d) ? buf[threadIdx.x - d] : 0;
    __syncthreads();
    buf[threadIdx.x] += t;
    __syncthreads();
  }
  if (i < cN_SRC) excl[i] = buf[threadIdx.x] - v;
  if (threadIdx.x == 255) bsum[blockIdx.x] = buf[255];
}
__global__ __launch_bounds__(256) void k_scan2(int* __restrict__ bsum, int nb) {
  __shared__ int buf[256];
  int v = (threadIdx.x < nb) ? bsum[threadIdx.x] : 0;
  buf[threadIdx.x] = v; __syncthreads();
  for (int d = 1; d < 256; d <<= 1) {
    int t = (threadIdx.x >= d) ? buf[threadIdx.x - d] : 0;
    __syncthreads();
    buf[threadIdx.x] += t;
    __syncthreads();
  }
  if (threadIdx.x < nb) bsum[threadIdx.x] = buf[threadIdx.x] - v;
}
__global__ void k_scan3(const int* __restrict__ excl, const int* __restrict__ bsum,
                        int* __restrict__ offs, int* __restrict__ cursor) {
  int i = blockIdx.x * 256 + threadIdx.x;
  if (i < cN_SRC) { int o = excl[i] + bsum[i >> 8]; offs[i] = o; cursor[i] = o; }
  else if (i == cN_SRC) offs[cN_SRC] = cE_DOM;
}
__global__ void k_scatter(const int* __restrict__ dme1, int* __restrict__ cursor,
                          int* __restrict__ eid) {
  int e = blockIdx.x * blockDim.x + threadIdx.x;
  if (e < cE_DOM) {
    int pos = atomicAdd(&cursor[dme1[e]], 1);
    eid[pos] = e;
  }
}

// ---------------- edge kernel: gather-sum xW rows into 32 bins, add xsl/ylin
// gathers, write bf16 msg, BN partials. No GEMM here. 20 KB LDS -> 8 blocks/CU.
__global__ __launch_bounds__(256, 8) void k_edge(
    const unsigned short* __restrict__ xw, const int* __restrict__ nme0,
    const int* __restrict__ ii, const int* __restrict__ bnd,
    const unsigned short* __restrict__ xsl, const unsigned short* __restrict__ yl,
    const int* __restrict__ dme0, const int* __restrict__ dme1,
    unsigned short* __restrict__ msg, float* __restrict__ partials) {
  __shared__ float sV[32 * HH];  // 16 KB
  __shared__ float sAux[1024];   // 4 KB: sIdx during gather, sBN after
  int* sIdx = (int*)sAux;
  int tid = threadIdx.x, lane = tid & 63, wv = tid >> 6;
  int e0 = blockIdx.x * 32;
  int j0 = bnd[e0], j1 = bnd[e0 + 32];
  int c0 = lane * 2;

  for (int i = tid; i < 32 * HH; i += 256) sV[i] = 0.f;
  __syncthreads();

  const unsigned* xwu = (const unsigned*)xw;
  for (int jb = j0; jb < j1; jb += 256) {
    int cn = min(256, j1 - jb);
    if (tid < cn) { sIdx[tid] = nme0[jb + tid]; sIdx[256 + tid] = ii[jb + tid] - e0; }
    __syncthreads();
    int jj = wv;
    for (; jj + 12 < cn; jj += 16) {
      int r0 = sIdx[jj],      b0 = sIdx[256 + jj];
      int r1 = sIdx[jj + 4],  b1 = sIdx[256 + jj + 4];
      int r2 = sIdx[jj + 8],  b2 = sIdx[256 + jj + 8];
      int r3 = sIdx[jj + 12], b3 = sIdx[256 + jj + 12];
      unsigned u0 = xwu[(size_t)r0 * 64 + lane];
      unsigned u1 = xwu[(size_t)r1 * 64 + lane];
      unsigned u2 = xwu[(size_t)r2 * 64 + lane];
      unsigned u3 = xwu[(size_t)r3 * 64 + lane];
      atomicAdd(&sV[b0 * HH + c0], bf2f(u0 & 0xffff));
      atomicAdd(&sV[b0 * HH + c0 + 1], bf2f(u0 >> 16));
      atomicAdd(&sV[b1 * HH + c0], bf2f(u1 & 0xffff));
      atomicAdd(&sV[b1 * HH + c0 + 1], bf2f(u1 >> 16));
      atomicAdd(&sV[b2 * HH + c0], bf2f(u2 & 0xffff));
      atomicAdd(&sV[b2 * HH + c0 + 1], bf2f(u2 >> 16));
      atomicAdd(&sV[b3 * HH + c0], bf2f(u3 & 0xffff));
      atomicAdd(&sV[b3 * HH + c0 + 1], bf2f(u3 >> 16));
    }
    for (; jj < cn; jj += 4) {
      int r0 = sIdx[jj], b0 = sIdx[256 + jj];
      unsigned u0 = xwu[(size_t)r0 * 64 + lane];
      atomicAdd(&sV[b0 * HH + c0], bf2f(u0 & 0xffff));
      atomicAdd(&sV[b0 * HH + c0 + 1], bf2f(u0 >> 16));
    }
    __syncthreads();
  }
  __syncthreads();

  const unsigned* xslu = (const unsigned*)xsl;
  const unsigned* ylu = (const unsigned*)yl;
  float s0 = 0.f, s1 = 0.f, q0 = 0.f, q1 = 0.f;
#pragma unroll
  for (int i = 0; i < 8; i++) {
    int le = wv * 8 + i;
    int e = e0 + le;
    int s = dme0[e], t = dme1[e];
    unsigned xs = xslu[(size_t)s * 64 + lane];
    unsigned yy = ylu[(size_t)t * 64 + lane];
    float m0 = sV[le * HH + c0] + bf2f(xs & 0xffff) + bf2f(yy & 0xffff);
    float m1 = sV[le * HH + c0 + 1] + bf2f(xs >> 16) + bf2f(yy >> 16);
    ushort2 u; u.x = f2bf(m0); u.y = f2bf(m1);
    *(ushort2*)(msg + (size_t)e * HH + c0) = u;
    s0 += m0; q0 += m0 * m0; s1 += m1; q1 += m1 * m1;
  }
  __syncthreads();
  float* sBN = sAux;
  *(float4*)(&sBN[wv * 256 + lane * 4]) = make_float4(s0, q0, s1, q1);
  __syncthreads();
  partials[(size_t)blockIdx.x * 256 + tid] =
      sBN[tid] + sBN[256 + tid] + sBN[512 + tid] + sBN[768 + tid];
}

// ---------------- BN stat reduction + scale/shift
__global__ __launch_bounds__(256) void k_bnred1(const float* __restrict__ partials,
                                                float* __restrict__ part2, int nb) {
  float s = 0.f;
  for (int b = blockIdx.x; b < nb; b += 64) s += partials[(size_t)b * 256 + threadIdx.x];
  part2[blockIdx.x * 256 + threadIdx.x] = s;
}
__global__ __launch_bounds__(256) void k_bnfinal(const float* __restrict__ part2,
                                                 const float* __restrict__ bnw,
                                                 const float* __restrict__ bnb,
                                                 float* __restrict__ ss) {
  __shared__ float L[256];
  float s = 0.f;
  for (int b = 0; b < 64; b++) s += part2[b * 256 + threadIdx.x];
  L[threadIdx.x] = s; __syncthreads();
  if (threadIdx.x < HH) {
    int c = threadIdx.x;
    float sum = L[2 * c], sq = L[2 * c + 1];
    float mean = sum / (float)cE_DOM;
    float var = sq / (float)cE_DOM - mean * mean;
    float sc = bnw[c] * rsqrtf(var + 1e-5f);
    float sh = bnb[c] - mean * sc;
    ss[2 * c] = sc; ss[2 * c + 1] = sh;
  }
}

// ---------------- final: one wave per target, sum relu(bn(msg)) over CSR edges
__global__ __launch_bounds__(256) void k_out(const unsigned short* __restrict__ msg,
                                             const int* __restrict__ offs,
                                             const int* __restrict__ eid,
                                             const float* __restrict__ ss,
                                             float* __restrict__ out) {
  int wv = threadIdx.x >> 6, lane = threadIdx.x & 63;
  int t = blockIdx.x * 4 + wv;
  if (t >= cN_Y) return;
  int c0 = lane * 2;
  float sc0 = ss[c0 * 2 + 0], sh0 = ss[c0 * 2 + 1];
  float sc1 = ss[(c0 + 1) * 2 + 0], sh1 = ss[(c0 + 1) * 2 + 1];
  float a0 = 0.f, a1 = 0.f;
  int j0 = offs[t], j1 = offs[t + 1];
  for (int j = j0; j < j1; ++j) {
    int e = eid[j];
    ushort2 u = *(const ushort2*)(msg + (size_t)e * HH + c0);
    float m0 = fmaf(bf2f(u.x), sc0, sh0);
    float m1 = fmaf(bf2f(u.y), sc1, sh1);
    a0 += fmaxf(m0, 0.f);
    a1 += fmaxf(m1, 0.f);
  }
  *(float2*)(out + (size_t)t * HH + c0) = make_float2(a0, a1);
}

extern "C" void kernel_launch(void* const* d_in, const int* in_sizes, int n_in,
                              void* d_out, int out_size, void* d_ws, size_t ws_size,
                              hipStream_t stream) {
  const float* x     = (const float*)d_in[0];
  const float* y     = (const float*)d_in[1];
  const int* dom_ind = (const int*)d_in[2];
  const int* nme     = (const int*)d_in[3];
  const int* ii      = (const int*)d_in[4];
  const int* dme     = (const int*)d_in[5];
  const float* Wxsum = (const float*)d_in[6];
  const float* Wxint = (const float*)d_in[7];
  const float* Wy    = (const float*)d_in[8];
  const float* bnw   = (const float*)d_in[9];
  const float* bnb   = (const float*)d_in[10];
  float* out = (float*)d_out;

  char* ws = (char*)d_ws;
  size_t o = 0;
  auto alloc = [&](size_t bytes) -> void* {
    void* p = ws + o;
    o = (o + bytes + 255) & ~(size_t)255;
    return p;
  };
  float* xsum   = (float*)alloc((size_t)cN_SRC * HH * 4);
  unsigned short* xsl = (unsigned short*)alloc((size_t)cN_SRC * HH * 2);
  unsigned short* ylin = (unsigned short*)alloc((size_t)cN_Y * HH * 2);
  unsigned short* xw = (unsigned short*)alloc((size_t)cN_X * HH * 2);
  unsigned short* msg = (unsigned short*)alloc((size_t)cE_DOM * HH * 2);
  int* bnd      = (int*)alloc((size_t)(cN_INT + 1) * 4);
  int* cnt      = (int*)alloc((size_t)cN_SRC * 4);
  int* excl     = (int*)alloc((size_t)cN_SRC * 4);
  int* bsum     = (int*)alloc(256 * 4);
  int* offs     = (int*)alloc((size_t)(cN_SRC + 1) * 4);
  int* cursor   = (int*)alloc((size_t)cN_SRC * 4);
  int* eid      = (int*)alloc((size_t)cE_DOM * 4);
  const int neb = cE_DOM / 32;  // 15625 edge blocks
  float* partials = (float*)alloc((size_t)neb * 256 * 4);
  float* part2  = (float*)alloc(64 * 256 * 4);
  float* ssbuf  = (float*)alloc(256 * 4);
  unsigned short* Wbf = (unsigned short*)alloc(3 * 16384 * 2);

  hipMemsetAsync(xsum, 0, (size_t)cN_SRC * HH * 4, stream);
  hipMemsetAsync(cnt, 0, (size_t)cN_SRC * 4, stream);

  k_wcast<<<48, 256, 0, stream>>>(Wxsum, Wy, Wxint, Wbf);
  k_segsum_x<<<(cN_X + 255) / 256, 256, 0, stream>>>(x, dom_ind, xsum);
  k_gemm128b<<<(cN_X + 63) / 64, 256, 0, stream>>>(x, Wbf + 32768, xw, cN_X);
  k_gemm128b<<<(cN_SRC + 63) / 64, 256, 0, stream>>>(xsum, Wbf, xsl, cN_SRC);
  k_gemm128b<<<(cN_Y + 63) / 64, 256, 0, stream>>>(y, Wbf + 16384, ylin, cN_Y);
  k_bounds<<<(cN_INT + 1 + 255) / 256, 256, 0, stream>>>(ii, bnd);
  k_hist<<<(cE_DOM + 255) / 256, 256, 0, stream>>>(dme + cE_DOM, cnt);
  k_scan1<<<(cN_SRC + 255) / 256, 256, 0, stream>>>(cnt, bsum, excl);
  k_scan2<<<1, 256, 0, stream>>>(bsum, (cN_SRC + 255) / 256);
  k_scan3<<<(cN_SRC + 1 + 255) / 256, 256, 0, stream>>>(excl, bsum, offs, cursor);
  k_scatter<<<(cE_DOM + 255) / 256, 256, 0, stream>>>(dme + cE_DOM, cursor, eid);
  k_edge<<<neb, 256, 0, stream>>>(xw, nme, ii, bnd, xsl, ylin,
                                  dme, dme + cE_DOM, msg, partials);
  k_bnred1<<<64, 256, 0, stream>>>(partials, part2, neb);
  k_bnfinal<<<1, 256, 0, stream>>>(part2, bnw, bnb, ssbuf);
  k_out<<<(cN_Y + 3) / 4, 256, 0, stream>>>(msg, offs, eid, ssbuf, out);
}